// Round 6
// baseline (14606.915 us; speedup 1.0000x reference)
//
#include <hip/hip_runtime.h>
#include <cstdint>

#define B_SZ  1024
#define S_LEN 200
#define H_DIM 256

typedef short s16x8 __attribute__((ext_vector_type(8)));
typedef float f32x4 __attribute__((ext_vector_type(4)));

__device__ __forceinline__ short f2bf(float f){
  uint32_t u = __float_as_uint(f);
  u += 0x7FFFu + ((u >> 16) & 1u);   // RNE
  return (short)(u >> 16);
}
__device__ __forceinline__ float sigm(float x){
  return __fdividef(1.f, 1.f + __expf(-x));
}
__device__ __forceinline__ float tanh_f(float x){
  return 1.f - __fdividef(2.f, __expf(2.f*x) + 1.f);
}

// ---- prep: fp32 -> bf16 weights (split x/h parts) + zero hx/flags -------
// wx   [768][256]: rows 0-255 Wr(:,0:256), 256-511 Wz, 512-767 Wn
// wrzh [512][256]: rows 0-255 Wr(:,256:512), 256-511 Wz(:,256:512)
// wnh  [256][256]: Wn(:,256:512)
// w1b  [128][512]
__global__ __launch_bounds__(256) void prep_kernel(
    const float* __restrict__ Wr, const float* __restrict__ Wz,
    const float* __restrict__ Wn, const float* __restrict__ W1,
    short* __restrict__ wx, short* __restrict__ wrzh,
    short* __restrict__ wnh, short* __restrict__ w1b,
    unsigned int* __restrict__ hx_u, int* __restrict__ flags){
  const int NWX=196608, NRZ=131072, NN=65536, NW1=65536;
  const int NWT=NWX+NRZ+NN+NW1;        // 458752
  int i = blockIdx.x*256 + threadIdx.x;
  if(i < NWX){
    int o=i>>8, k=i&255;
    float v = (o<256)? Wr[o*512+k] : (o<512)? Wz[(o-256)*512+k] : Wn[(o-512)*512+k];
    wx[i]=f2bf(v);
  } else if(i < NWX+NRZ){
    int j=i-NWX; int o=j>>8, k=j&255;
    float v=(o<256)? Wr[o*512+256+k] : Wz[(o-256)*512+256+k];
    wrzh[j]=f2bf(v);
  } else if(i < NWX+NRZ+NN){
    int j=i-NWX-NRZ; int o=j>>8, k=j&255;
    wnh[j]=f2bf(Wn[o*512+256+k]);
  } else if(i < NWT){
    int j=i-NWX-NRZ-NN;
    w1b[j]=f2bf(W1[j]);
  } else if(i < NWT+131072){
    hx_u[i-NWT]=0u;                    // h exchange buffer = h0 = 0
  } else if(i < NWT+131072+2048){
    flags[i-NWT-131072]=0;             // sync counters
  }
}

// ---- attention scores: relu(combined @ W1^T + b1) @ W2 ------------------
__global__ __launch_bounds__(256) void scores_kernel(
    const float* __restrict__ hs, const float* __restrict__ tgt,
    const short* __restrict__ w1, const float* __restrict__ b1,
    const float* __restrict__ w2, float* __restrict__ scores){
  const int tid = threadIdx.x;
  const int lane = tid & 63;
  const int wv  = tid >> 6;
  const int l15 = lane & 15;
  const int q   = lane >> 4;
  const int gw  = blockIdx.x * 4 + wv;    // 0..3199
  float b1v[8], w2v[8];
  #pragma unroll
  for(int nt=0;nt<8;nt++){ b1v[nt]=b1[nt*16+l15]; w2v[nt]=w2[nt*16+l15]; }
  const short* w1p = w1 + (size_t)l15*512 + q*8;
  for(int it=0; it<2; it++){
    int mt0 = gw + it*3200;
    int mt1 = mt0 + 6400;
    int m0  = mt0*16 + l15;
    int m1  = mt1*16 + l15;
    int bA  = m0 / S_LEN, sA = m0 - bA*S_LEN;
    int bB  = m1 / S_LEN, sB = m1 - bB*S_LEN;
    const float* arowA = hs  + ((size_t)bA*S_LEN + sA)*H_DIM;
    const float* trowA = tgt + (size_t)bA*H_DIM;
    const float* arowB = hs  + ((size_t)bB*S_LEN + sB)*H_DIM;
    const float* trowB = tgt + (size_t)bB*H_DIM;
    f32x4 acc[2][8];
    #pragma unroll
    for(int u=0;u<2;u++)
      #pragma unroll
      for(int nt=0;nt<8;nt++) acc[u][nt] = (f32x4){0.f,0.f,0.f,0.f};
    for(int kt=0;kt<16;kt++){
      int k0 = kt*32 + q*8;
      const float* srcA = (k0 < H_DIM) ? (arowA + k0) : (trowA + (k0 - H_DIM));
      const float* srcB = (k0 < H_DIM) ? (arowB + k0) : (trowB + (k0 - H_DIM));
      float4 a0 = *(const float4*)(srcA);
      float4 a1 = *(const float4*)(srcA+4);
      float4 c0 = *(const float4*)(srcB);
      float4 c1 = *(const float4*)(srcB+4);
      s16x8 aA, aB;
      aA[0]=f2bf(a0.x); aA[1]=f2bf(a0.y); aA[2]=f2bf(a0.z); aA[3]=f2bf(a0.w);
      aA[4]=f2bf(a1.x); aA[5]=f2bf(a1.y); aA[6]=f2bf(a1.z); aA[7]=f2bf(a1.w);
      aB[0]=f2bf(c0.x); aB[1]=f2bf(c0.y); aB[2]=f2bf(c0.z); aB[3]=f2bf(c0.w);
      aB[4]=f2bf(c1.x); aB[5]=f2bf(c1.y); aB[6]=f2bf(c1.z); aB[7]=f2bf(c1.w);
      #pragma unroll
      for(int nt=0;nt<8;nt++){
        s16x8 bf = *(const s16x8*)(w1p + (size_t)nt*16*512 + kt*32);
        acc[0][nt] = __builtin_amdgcn_mfma_f32_16x16x32_bf16(aA, bf, acc[0][nt], 0, 0, 0);
        acc[1][nt] = __builtin_amdgcn_mfma_f32_16x16x32_bf16(aB, bf, acc[1][nt], 0, 0, 0);
      }
    }
    #pragma unroll
    for(int u=0;u<2;u++){
      float sr0=0.f, sr1=0.f, sr2=0.f, sr3=0.f;
      #pragma unroll
      for(int nt=0;nt<8;nt++){
        f32x4 h4 = acc[u][nt];
        sr0 += fmaxf(h4[0]+b1v[nt],0.f)*w2v[nt];
        sr1 += fmaxf(h4[1]+b1v[nt],0.f)*w2v[nt];
        sr2 += fmaxf(h4[2]+b1v[nt],0.f)*w2v[nt];
        sr3 += fmaxf(h4[3]+b1v[nt],0.f)*w2v[nt];
      }
      #pragma unroll
      for(int mask=1; mask<16; mask<<=1){
        sr0 += __shfl_xor(sr0, mask, 64);
        sr1 += __shfl_xor(sr1, mask, 64);
        sr2 += __shfl_xor(sr2, mask, 64);
        sr3 += __shfl_xor(sr3, mask, 64);
      }
      if(l15 < 4){
        float outv = (l15==0)?sr0:(l15==1)?sr1:(l15==2)?sr2:sr3;
        int mt = (u==0)?mt0:mt1;
        scores[(size_t)mt*16 + q*4 + l15] = outv;
      }
    }
  }
}

// ---- masked softmax over S per batch row --------------------------------
__global__ __launch_bounds__(256) void softmax_kernel(
    const float* __restrict__ scores, const int* __restrict__ lengths,
    float* __restrict__ att){
  const int b = blockIdx.x;
  const int s = threadIdx.x;
  const int lane = s & 63, wv = s >> 6;
  __shared__ float red[4];
  __shared__ float red2[4];
  float sc = -1e9f;
  if(s < S_LEN){
    float v = scores[(size_t)b*S_LEN + s];
    sc = (s < lengths[b]) ? v : -1e9f;
  }
  float mx = (s < S_LEN) ? sc : -INFINITY;
  #pragma unroll
  for(int mask=1; mask<64; mask<<=1) mx = fmaxf(mx, __shfl_xor(mx, mask, 64));
  if(lane==0) red[wv] = mx;
  __syncthreads();
  mx = fmaxf(fmaxf(red[0],red[1]), fmaxf(red[2],red[3]));
  float e = (s < S_LEN) ? expf(sc - mx) : 0.f;
  float sum = e;
  #pragma unroll
  for(int mask=1; mask<64; mask<<=1) sum += __shfl_xor(sum, mask, 64);
  if(lane==0) red2[wv] = sum;
  __syncthreads();
  sum = red2[0]+red2[1]+red2[2]+red2[3];
  if(s < S_LEN) att[(size_t)b*S_LEN + s] = e / sum;
}

// ---- GRU scan, 4-way hidden-dim split -----------------------------------
// 256 blocks x 512 threads. bid = slice*64 + group  (all 4 slices of a
// group share bid%8 -> same XCD for L2 locality; correctness uses
// agent-scope atomics so placement doesn't matter).
// Block owns h-cols [s*64, s*64+64): weights for r,z,n own cols live in
// LDS (96 KB). Full h and full r*h are exchanged per step via hx/rhx in
// global memory with two counter-flag syncs. 1 block/CU (163 KB LDS);
// grid 256 = CU count -> all blocks co-resident.
#define WL_OFF   0
#define XP_OFF   99840
#define HO_OFF   124928
#define U_OFF    129280
#define ATTC_OFF 163072
__global__ __launch_bounds__(512) void scan_kernel(
    const float* __restrict__ hs, const float* __restrict__ att,
    const short* __restrict__ wx, const short* __restrict__ wrzh,
    const short* __restrict__ wnh,
    const float* __restrict__ br, const float* __restrict__ bz,
    const float* __restrict__ bn, float* __restrict__ out,
    unsigned short* __restrict__ hx_s, unsigned short* __restrict__ rhx_s,
    int* __restrict__ flags){
  __shared__ __align__(16) char smem[163328];
  short*    wL    = (short*)(smem + WL_OFF);     // [192][260] r|z|n own rows
  _Float16* XP    = (_Float16*)(smem + XP_OFF);  // [4][16][196] x-proj + bias
  float*    hO    = (float*)(smem + HO_OFF);     // [16][68] own h fp32
  short*    xst   = (short*)(smem + U_OFF);      // [64][264] chunk A (union)
  short*    comb0 = (short*)(smem + U_OFF);      // [16][264] full h bf16
  short*    comb1 = (short*)(smem + U_OFF + 8448);   // [16][264] full r*h
  _Float16* zS    = (_Float16*)(smem + U_OFF + 16896); // [16][72] own z
  float*    attc  = (float*)(smem + ATTC_OFF);   // [4][16]

  const int tid  = threadIdx.x;
  const int lane = tid & 63;
  const int wv   = tid >> 6;          // 0..7
  const int l15  = lane & 15;
  const int q    = lane >> 4;
  const int bid  = blockIdx.x;
  const int s    = bid >> 6;          // slice 0..3
  const int g    = bid & 63;          // group 0..63
  const int b0   = g * 16;
  unsigned int* hx_u  = (unsigned int*)hx_s;
  unsigned int* rhx_u = (unsigned int*)rhx_s;
  int* flag_rh = flags + g*32;
  int* flag_h  = flags + g*32 + 16;

  // load own weights into LDS: rows 0-63 Wr_h, 64-127 Wz_h, 128-191 Wn_h
  for(int idx=tid; idx<192*32; idx+=512){
    int row = idx>>5, ck = (idx&31)*8;
    const short* src;
    if(row<64)       src = wrzh + (size_t)(s*64+row)*256 + ck;
    else if(row<128) src = wrzh + (size_t)(256 + s*64 + row-64)*256 + ck;
    else             src = wnh  + (size_t)(s*64 + row-128)*256 + ck;
    *(s16x8*)(wL + row*260 + ck) = *(const s16x8*)src;
  }
  // chunk-GEMM biases (own 192 outputs; pass0 = nt=wv, pass1 = nt=8+wv)
  float biasc0, biasc1=0.f;
  {
    int i0 = s*64 + (wv&3)*16 + l15;
    biasc0 = (wv<4)? br[i0] : bz[i0];
    if(wv<4) biasc1 = bn[s*64 + wv*16 + l15];
  }
  for(int i=tid;i<16*68;i+=512) hO[i]=0.f;

  for(int c=0;c<50;c++){
    const int t0=c*4;
    __syncthreads();                     // prior step's comb/zS reads done
    // stage x (4 steps x 16 rows) bf16 -> xst
    #pragma unroll
    for(int jj=0;jj<4;jj++){
      int idx = tid + jj*512;            // 0..2047
      int r = idx>>5, k=(idx&31)*8;      // r = tl*16+bl
      int bl=r&15, tl=r>>4;
      const float* src = hs + ((size_t)(b0+bl)*S_LEN + (t0+tl))*H_DIM + k;
      float4 v0=*(const float4*)src, v1=*(const float4*)(src+4);
      s16x8 xv;
      xv[0]=f2bf(v0.x); xv[1]=f2bf(v0.y); xv[2]=f2bf(v0.z); xv[3]=f2bf(v0.w);
      xv[4]=f2bf(v1.x); xv[5]=f2bf(v1.y); xv[6]=f2bf(v1.z); xv[7]=f2bf(v1.w);
      *(s16x8*)(xst + r*264 + k) = xv;
    }
    if(tid<64) attc[tid] = att[(size_t)(b0+(tid&15))*S_LEN + t0 + (tid>>4)];
    __syncthreads();                     // xst + attc ready
    // chunk GEMM: XP[tl][row][o] = x @ Wx_own^T + bias, o in [0,192)
    #pragma unroll
    for(int p=0;p<2;p++){
      if(p==1 && wv>=4) break;
      int nt = p*8 + wv;
      f32x4 xacc[4];
      #pragma unroll
      for(int tl=0;tl<4;tl++) xacc[tl]=(f32x4){0.f,0.f,0.f,0.f};
      #pragma unroll
      for(int kt=0;kt<8;kt++){
        const short* wrow = wx + (size_t)((nt>>2)*256 + s*64 + (nt&3)*16 + l15)*256 + kt*32+q*8;
        s16x8 bf0 = *(const s16x8*)wrow;
        #pragma unroll
        for(int tl=0;tl<4;tl++){
          s16x8 a = *(const s16x8*)(xst + (tl*16+l15)*264 + kt*32 + q*8);
          xacc[tl]=__builtin_amdgcn_mfma_f32_16x16x32_bf16(a,bf0,xacc[tl],0,0,0);
        }
      }
      int col = nt*16 + l15;
      float bias = (p==0)? biasc0 : biasc1;
      #pragma unroll
      for(int tl=0;tl<4;tl++)
        #pragma unroll
        for(int reg=0;reg<4;reg++)
          XP[(size_t)(tl*16 + q*4+reg)*196 + col] = (_Float16)(xacc[tl][reg] + bias);
    }
    __syncthreads();                     // XP ready; xst dead
    // ---- 4 recurrence steps ----
    for(int tl=0;tl<4;tl++){
      const int t = t0 + tl;
      // wait all slices published h(t-1), then build full-h A matrix
      if(tid==0 && t>0){
        while(__hip_atomic_load(flag_h, __ATOMIC_ACQUIRE, __HIP_MEMORY_SCOPE_AGENT) < 4*t)
          __builtin_amdgcn_s_sleep(1);
      }
      __syncthreads();
      {
        int row = tid>>5, pb = (tid&31)*4;
        #pragma unroll
        for(int j=0;j<4;j++){
          unsigned int v = __hip_atomic_load(&hx_u[(size_t)(g*16+row)*128 + pb + j],
                                             __ATOMIC_RELAXED, __HIP_MEMORY_SCOPE_AGENT);
          *(unsigned int*)(comb0 + row*264 + pb*2 + 2*j) = v;
        }
      }
      __syncthreads();                   // comb0 ready
      // GEMM1: full h @ [Wr_own;Wz_own]^T -> own r (wv<4) / z (wv>=4)
      f32x4 acc = (f32x4){0.f,0.f,0.f,0.f};
      #pragma unroll
      for(int kt=0;kt<8;kt++){
        s16x8 a = *(const s16x8*)(comb0 + l15*264 + kt*32+q*8);
        s16x8 b = *(const s16x8*)(wL + (wv*16+l15)*260 + kt*32+q*8);
        acc=__builtin_amdgcn_mfma_f32_16x16x32_bf16(a,b,acc,0,0,0);
      }
      {
        int oc = wv*16 + l15;            // 0..127 (r:0-63, z:64-127)
        #pragma unroll
        for(int reg=0;reg<4;reg++){
          int row = q*4+reg;
          float pre = acc[reg] + (float)XP[(size_t)(tl*16+row)*196 + oc];
          float gg = sigm(pre);
          if(wv<4){
            float rh = gg * hO[row*68 + oc];
            __hip_atomic_store(&rhx_s[(size_t)(g*16+row)*256 + s*64 + oc],
                               (unsigned short)f2bf(rh),
                               __ATOMIC_RELAXED, __HIP_MEMORY_SCOPE_AGENT);
          } else {
            zS[row*72 + (oc-64)] = (_Float16)(gg * attc[tl*16+row]);
          }
        }
      }
      __threadfence();
      __syncthreads();                   // all r*h stores drained
      if(tid==0){
        __hip_atomic_fetch_add(flag_rh, 1, __ATOMIC_RELEASE, __HIP_MEMORY_SCOPE_AGENT);
        while(__hip_atomic_load(flag_rh, __ATOMIC_ACQUIRE, __HIP_MEMORY_SCOPE_AGENT) < 4*(t+1))
          __builtin_amdgcn_s_sleep(1);
      }
      __syncthreads();
      {
        int row = tid>>5, pb = (tid&31)*4;
        #pragma unroll
        for(int j=0;j<4;j++){
          unsigned int v = __hip_atomic_load(&rhx_u[(size_t)(g*16+row)*128 + pb + j],
                                             __ATOMIC_RELAXED, __HIP_MEMORY_SCOPE_AGENT);
          *(unsigned int*)(comb1 + row*264 + pb*2 + 2*j) = v;
        }
      }
      __syncthreads();                   // comb1 ready
      // GEMM2 (waves 0-3): full r*h @ Wn_own^T -> own n; h update
      if(wv<4){
        f32x4 acc2 = (f32x4){0.f,0.f,0.f,0.f};
        #pragma unroll
        for(int kt=0;kt<8;kt++){
          s16x8 a = *(const s16x8*)(comb1 + l15*264 + kt*32+q*8);
          s16x8 b = *(const s16x8*)(wL + (128 + wv*16+l15)*260 + kt*32+q*8);
          acc2=__builtin_amdgcn_mfma_f32_16x16x32_bf16(a,b,acc2,0,0,0);
        }
        int nc = wv*16 + l15;            // own h col 0..63
        #pragma unroll
        for(int reg=0;reg<4;reg++){
          int row = q*4+reg;
          float nv = tanh_f(acc2[reg] + (float)XP[(size_t)(tl*16+row)*196 + 128+nc]);
          float z  = (float)zS[row*72+nc];
          float hp = hO[row*68+nc];
          float hn = fmaf(z, nv-hp, hp);
          hO[row*68+nc]=hn;
          __hip_atomic_store(&hx_s[(size_t)(g*16+row)*256 + s*64 + nc],
                             (unsigned short)f2bf(hn),
                             __ATOMIC_RELAXED, __HIP_MEMORY_SCOPE_AGENT);
        }
      }
      __threadfence();
      __syncthreads();                   // h stores drained; comb1 reads done
      if(tid==0)
        __hip_atomic_fetch_add(flag_h, 1, __ATOMIC_RELEASE, __HIP_MEMORY_SCOPE_AGENT);
    }
  }
  __syncthreads();
  {  // own 64-col fp32 slice of the output
    int row = tid>>5, cc = (tid&31)*2;
    float* op = out + (size_t)(b0+row)*H_DIM + s*64 + cc;
    op[0] = hO[row*68 + cc];
    op[1] = hO[row*68 + cc + 1];
  }
}

extern "C" void kernel_launch(void* const* d_in, const int* in_sizes, int n_in,
                              void* d_out, int out_size, void* d_ws, size_t ws_size,
                              hipStream_t stream) {
  const float* hs  = (const float*)d_in[0];
  const float* tgt = (const float*)d_in[1];
  const int*   len = (const int*)d_in[2];
  const float* W1  = (const float*)d_in[3];
  const float* b1  = (const float*)d_in[4];
  const float* W2  = (const float*)d_in[5];
  const float* Wr  = (const float*)d_in[6];
  const float* br  = (const float*)d_in[7];
  const float* Wz  = (const float*)d_in[8];
  const float* bz  = (const float*)d_in[9];
  const float* Wn  = (const float*)d_in[10];
  const float* bn  = (const float*)d_in[11];
  float* out = (float*)d_out;
  // ws: wx[196608]s | wrzh[131072]s | wnh[65536]s | w1b[65536]s |
  //     scores[204800]f | att[204800]f | hx[262144]s | rhx[262144]s | flags[2048]i
  short* wx   = (short*)d_ws;
  short* wrzh = wx + 196608;
  short* wnh  = wrzh + 131072;
  short* w1b  = wnh + 65536;
  float* scores = (float*)(w1b + 65536);
  float* att    = scores + (size_t)B_SZ*S_LEN;
  unsigned short* hx_s  = (unsigned short*)(att + (size_t)B_SZ*S_LEN);
  unsigned short* rhx_s = hx_s + 262144;
  int* flags = (int*)(rhx_s + 262144);
  prep_kernel<<<2312, 256, 0, stream>>>(Wr, Wz, Wn, W1, wx, wrzh, wnh, w1b,
                                        (unsigned int*)hx_s, flags);
  scores_kernel<<<800, 256, 0, stream>>>(hs, tgt, w1b, b1, W2, scores);
  softmax_kernel<<<1024, 256, 0, stream>>>(scores, len, att);
  scan_kernel<<<256, 512, 0, stream>>>(hs, att, wx, wrzh, wnh, br, bz, bn, out,
                                       hx_s, rhx_s, flags);
}